// Round 4
// baseline (1146.597 us; speedup 1.0000x reference)
//
#include <hip/hip_runtime.h>

// ResidualConvLSTM2D on MI355X (gfx950).
// Fused per-timestep implicit GEMM: z = conv3x3([x_t || h_{t-1}], [Wx || Wh]) via
// bf16 MFMA (16x16x32), fp32 LSTM cell, fp32 residual 1x1 conv.
//
// R7: R6 (counted-vmcnt DMA pipeline) was NEUTRAL vs R5 - dur/FETCH/WRITE all
// identical. All three schedules pin at (FETCH+WRITE)/~2.3TB/s; the invariant
// is TCC-path BYTES. WRITE_SIZE=66.5MB vs ~10MB of actual stores: the excess
// tracks the 143MB/dispatch global_load_lds request volume -> theory: the LDS-
// DMA path doesn't keep the (trivially L2-sized, 0.57MB) weight image L2-
// resident, so weight reads transit the TCC/fabric path every phase.
// Fix: reg-staged weight loads (T14): per thread 2-3 global_load_dwordx4 into
// regs at phase START (normal loads -> L2-allocating; 31/32 blocks per XCD hit
// L2), counted-vmcnt wait + ds_write_b128 at phase END into double-buffered
// LDS tile. One barrier per phase. Everything else unchanged from R5/R6.
//
// ws layout (<4.79 MB of ~8 MB):
//   [0, 573440)          WT staged bf16 [28][256][40] (step 27 zeroed)
//   [589824, +2MB)       h ping  bf16 [4][64][64][64]
//   [2686976, +2MB)      h pong  bf16
// Cell state c (fp32) lives inside d_out: c_t at out[b][t][...] (read before
// that address is overwritten with the output), c_{t+1} into slab t+1.
#define B_ 4
#define T_ 16
#define H_ 64
#define W_ 64
#define CIN 32
#define F_ 64
#define NCH 256
#define KSTEPS 27
#define NPHASE 14
#define WSTEP 10240           // shorts per K-step weight image [256][40]
#define PHS   20480           // shorts per phase (2 K-steps)
#define TSLAB (H_ * W_ * F_)  // floats between (b,t) and (b,t+1)

#define OFF_H0 589824
#define OFF_H1 2686976

typedef __attribute__((ext_vector_type(8))) short short8;
typedef __attribute__((ext_vector_type(4))) float floatx4;

__device__ __forceinline__ unsigned short f2bf(float f) {
  union { float f; unsigned u; } v; v.f = f;
  unsigned r = v.u + 0x7FFFu + ((v.u >> 16) & 1u);   // round-to-nearest-even
  return (unsigned short)(r >> 16);
}

// tanh via hardware exp2: tanh(z) = 1 - 2/(exp(2z)+1). rcp approx (~1 ulp) is
// far inside the 4e-2 abs threshold. Saturates correctly for |z| large.
__device__ __forceinline__ float tanh_fast(float z) {
  float e = __expf(2.0f * z);
  return 1.0f - 2.0f * __builtin_amdgcn_rcpf(e + 1.0f);
}

// Staging image: WT[s][n][c], c in [0,40); c<32 -> weight for k = s*32+c of
// output channel n (k = tap*96 + ch; ch<32 from Wx else Wh); pad/step-27 -> 0.
__global__ void prep_weights(const float* __restrict__ Wx, const float* __restrict__ Wh,
                             unsigned short* __restrict__ WT) {
  int idx = blockIdx.x * 256 + threadIdx.x;            // 0..286719
  int s = idx / WSTEP;
  int r = idx - s * WSTEP;
  int n = r / 40;
  int c = r - n * 40;
  unsigned short v = 0;
  if (c < 32 && s < KSTEPS) {
    int k  = s * 32 + c;
    int g  = k / 96;
    int ch = k - g * 96;
    float f = (ch < CIN) ? Wx[(g * CIN + ch) * NCH + n]
                         : Wh[(g * F_ + (ch - CIN)) * NCH + n];
    v = f2bf(f);
  }
  WT[idx] = v;
}

// Zero h ping+pong (4 MB in ws).
__global__ void prep_zero_h(float4* __restrict__ p) {
  int idx = blockIdx.x * 256 + threadIdx.x;
  p[idx] = make_float4(0.f, 0.f, 0.f, 0.f);
}

// Zero c0 = out slabs [b][0][...].
__global__ void prep_zero_c(float* __restrict__ out) {
  int idx = blockIdx.x * 256 + threadIdx.x;            // float4 units
  int b = idx >> 16;
  int i = idx & 65535;
  ((float4*)(out + (size_t)b * (T_ * TSLAB)))[i] = make_float4(0.f, 0.f, 0.f, 0.f);
}

// Load one phase tile (40960 B = 2560 dwordx4) into regs: threads 0..1023 take
// slots {tid, tid+1024}, threads 0..511 additionally slot tid+2048.
// Normal vector loads -> L1/L2 allocate (this is the point of R7).
__device__ __forceinline__ void load_ph(const unsigned short* __restrict__ src,
                                        uint4 (&r)[3], int tid) {
  const uint4* s = (const uint4*)src;
  r[0] = s[tid];
  r[1] = s[tid + 1024];
  if (tid < 512) r[2] = s[tid + 2048];
}

// Mirror the same linear slot mapping into LDS (consecutive 16B per lane:
// 2-way bank aliasing = free).
__device__ __forceinline__ void write_ph(short* dst, uint4 (&r)[3], int tid) {
  uint4* d = (uint4*)dst;
  d[tid]        = r[0];
  d[tid + 1024] = r[1];
  if (tid < 512) d[tid + 2048] = r[2];
}

__global__ __launch_bounds__(1024, 1)
void step_kernel(const float* __restrict__ x, const float* __restrict__ bias,
                 const float* __restrict__ Wp, const float* __restrict__ bp,
                 const unsigned short* __restrict__ WT,
                 const unsigned short* __restrict__ hprev,
                 unsigned short* __restrict__ hnew,
                 float* __restrict__ out, int t)
{
  // LDS: patch [4][34][104] sh (28288) | wb0 [2][256][40] sh (40960) | wb1.
  // epilogue reuse: gact [256][68] fp32 (69632 B) at 0, WpL 8 KB at 69632.
  __shared__ __align__(16) char smem[110208];
  short* patch = (short*)smem;
  short* wb0   = (short*)(smem + 28288);
  short* wb1   = (short*)(smem + 69248);
  float* gact  = (float*)smem;
  float* WpL   = (float*)(smem + 69632);

  const int tid  = threadIdx.x;
  const int w    = tid >> 6;               // 0..15
  const int lane = tid & 63;
  const int quad = lane >> 4;
  const int lr   = lane & 15;
  const int gate = w >> 2;                 // wave's gate (i,f,c,o)
  const int mq   = w & 3;                  // wave's M-quarter (16 pixels)

  // bijective XCD swizzle: 256 blocks, 8 XCDs, 32 consecutive bids per XCD.
  const int raw = blockIdx.x;
  const int bid = (raw & 7) * 32 + (raw >> 3);
  const int b   = bid >> 6;
  const int rem = bid & 63;
  const int y0  = (rem >> 1) << 1;   // 2-row tile
  const int x0  = (rem & 1) << 5;    // 32-col half

  uint4 rA[3], rB[3];

  // ---- issue phase-0 weight loads (T0 -> rA) immediately
  load_ph(WT, rA, tid);
  __builtin_amdgcn_sched_barrier(0);

  // ---- stage input patch: 4 rows x 34 cols x 96 ch (x bf16 | h bf16),
  // split per entry into x-half / h-half across 272 threads.
  if (tid < 272) {
    int e = tid >> 1, half = tid & 1;
    int sy = e / 34, sx = e - sy * 34;
    int yy = y0 + sy - 1, xx = x0 + sx - 1;
    short* dst = patch + e * 104;
    bool in = (yy >= 0 && yy < H_ && xx >= 0 && xx < W_);
    if (half == 0) {                      // x channels 0..31 -> bf16
      if (in) {
        const float4* xs = (const float4*)(x + ((((b * T_ + t) * H_ + yy) * W_ + xx) * CIN));
        #pragma unroll
        for (int j = 0; j < 4; j++) {
          float4 f0 = xs[2 * j];
          float4 f1 = xs[2 * j + 1];
          union { short8 v; unsigned short u[8]; } pk;
          pk.u[0] = f2bf(f0.x); pk.u[1] = f2bf(f0.y); pk.u[2] = f2bf(f0.z); pk.u[3] = f2bf(f0.w);
          pk.u[4] = f2bf(f1.x); pk.u[5] = f2bf(f1.y); pk.u[6] = f2bf(f1.z); pk.u[7] = f2bf(f1.w);
          ((short8*)dst)[j] = pk.v;
        }
      } else {
        uint4 z = make_uint4(0, 0, 0, 0);
        uint4* d4 = (uint4*)dst;
        #pragma unroll
        for (int j = 0; j < 4; j++) d4[j] = z;
      }
    } else {                              // h channels (already bf16)
      uint4* d2 = (uint4*)(dst + 32);
      if (in) {
        const uint4* hs = (const uint4*)(hprev + ((b * H_ + yy) * W_ + xx) * F_);
        #pragma unroll
        for (int j = 0; j < 8; j++) d2[j] = hs[j];
      } else {
        uint4 z = make_uint4(0, 0, 0, 0);
        #pragma unroll
        for (int j = 0; j < 8; j++) d2[j] = z;
      }
    }
  }

  // ---- issue phase-1 weight loads (T1 -> rB)
  load_ph(WT + PHS, rB, tid);

  float bias_r[4];
  #pragma unroll
  for (int nf = 0; nf < 4; nf++) bias_r[nf] = bias[gate * 64 + nf * 16 + lr];

  floatx4 acc[4];
  #pragma unroll
  for (int nf = 0; nf < 4; nf++) acc[nf] = (floatx4){0.f, 0.f, 0.f, 0.f};

  // wave's A-row (pixel) for the MFMA A operand
  const int px = mq * 16 + lr;            // 0..63
  const int ty = px >> 5, tx = px & 31;

  // ---- prologue drain: patch + T0 + T1 + bias all retired, then commit T0.
  asm volatile("s_waitcnt vmcnt(0) lgkmcnt(0)" ::: "memory");
  __builtin_amdgcn_sched_barrier(0);
  write_ph(wb0, rA, tid);
  asm volatile("s_waitcnt lgkmcnt(0)" ::: "memory");
  __builtin_amdgcn_sched_barrier(0);
  __builtin_amdgcn_s_barrier();
  __builtin_amdgcn_sched_barrier(0);

  // ---- K loop: 14 phases of 2 K-steps (BK=64) over K=864.
  // Phase p: issue T(p+2) loads (parity p&1 -> rA/rB), compute from buf[p&1],
  // counted-vmcnt wait so T(p+1) regs are landed (one full phase of cover),
  // ds_write T(p+1) -> buf[(p+1)&1], lgkm drain, barrier. Never vmcnt(0)
  // mid-loop while newer loads fly.
  const unsigned short* wsrc = WT + 2 * PHS;
  for (int p = 0; p < NPHASE; p++) {
    short* cur = (p & 1) ? wb1 : wb0;
    short* nxt = (p & 1) ? wb0 : wb1;
    if (p < NPHASE - 2) {
      if ((p & 1) == 0) load_ph(wsrc, rA, tid);
      else              load_ph(wsrc, rB, tid);
      wsrc += PHS;
      __builtin_amdgcn_sched_barrier(0);   // pin issue point at phase start
    }
    int s0 = 2 * p;
    #pragma unroll
    for (int half = 0; half < 2; half++) {
      int s = s0 + half;
      if (s < KSTEPS) {
        int g  = s / 3;
        int c0 = (s - g * 3) * 32;
        int dy = g / 3, dx = g - dy * 3;
        short8 afr = *(const short8*)(patch + ((ty + dy) * 34 + tx + dx) * 104 + c0 + quad * 8);
        #pragma unroll
        for (int nf = 0; nf < 4; nf++) {
          short8 bfr = *(const short8*)(cur + half * WSTEP + (gate * 64 + nf * 16 + lr) * 40 + quad * 8);
          acc[nf] = __builtin_amdgcn_mfma_f32_16x16x32_bf16(afr, bfr, acc[nf], 0, 0, 0);
        }
      }
    }
    __builtin_amdgcn_sched_barrier(0);
    if (p < NPHASE - 1) {
      if (p < NPHASE - 2) {
        // newer T(p+2) loads stay in flight: 3 for tid<512 waves, else 2.
        if (tid < 512) asm volatile("s_waitcnt vmcnt(3)" ::: "memory");
        else           asm volatile("s_waitcnt vmcnt(2)" ::: "memory");
      } else {
        asm volatile("s_waitcnt vmcnt(0)" ::: "memory");   // tail: nothing newer
      }
      __builtin_amdgcn_sched_barrier(0);
      if ((p & 1) == 0) write_ph(nxt, rB, tid);   // T(p+1) parity = !(p&1)
      else              write_ph(nxt, rA, tid);
    }
    asm volatile("s_waitcnt lgkmcnt(0)" ::: "memory");
    __builtin_amdgcn_sched_barrier(0);
    __builtin_amdgcn_s_barrier();
    __builtin_amdgcn_sched_barrier(0);
  }

  // ---- epilogue phase 1: activations -> gact[(gate*64+px)*68 + ch], WpL
  #pragma unroll
  for (int nf = 0; nf < 4; nf++)
    #pragma unroll
    for (int r = 0; r < 4; r++) {
      int mm = quad * 4 + r;                      // D row = quad*4 + reg
      float z = acc[nf][r] + bias_r[nf];
      float a;
      if (gate == 2) a = tanh_fast(z);            // candidate gate
      else {                                      // hard_sigmoid for i, f, o
        a = __builtin_fmaf(z, 0.2f, 0.5f);
        a = fminf(fmaxf(a, 0.f), 1.f);
      }
      gact[(gate * 64 + mq * 16 + mm) * 68 + nf * 16 + lr] = a;
    }
  if (tid < 512)                                  // Wp -> LDS (512 float4)
    ((float4*)WpL)[tid] = ((const float4*)Wp)[tid];

  const int mloc = tid >> 4;                      // pixel in tile (0..63)
  const int cb   = (tid & 15) * 4;                // 4-channel slice
  const int tyo  = mloc >> 5, txo = mloc & 31;
  const int gy   = y0 + tyo, gx = x0 + txo;
  const int hbase   = ((b * H_ + gy) * W_ + gx) * F_ + cb;
  const int outbase = (((b * T_ + t) * H_ + gy) * W_ + gx) * F_ + cb;

  // prefetch x (residual) and c_t (global) before the barrier
  float xv[32];
  {
    const float4* xs = (const float4*)(x + ((((b * T_ + t) * H_ + gy) * W_ + gx) * CIN));
    #pragma unroll
    for (int j = 0; j < 8; j++) {
      float4 f = xs[j];
      xv[4 * j] = f.x; xv[4 * j + 1] = f.y; xv[4 * j + 2] = f.z; xv[4 * j + 3] = f.w;
    }
  }
  float4 co4 = *(const float4*)(out + outbase);

  __syncthreads();                                // gact + WpL visible

  // ---- residual 1x1 conv (fp32), 4 output channels per thread
  float res[4];
  #pragma unroll
  for (int j = 0; j < 4; j++) res[j] = bp[cb + j];
  #pragma unroll
  for (int ci = 0; ci < 32; ci++) {
    float xf = xv[ci];
    float4 wv = *(const float4*)(WpL + ci * 64 + cb);
    res[0] += xf * wv.x; res[1] += xf * wv.y; res[2] += xf * wv.z; res[3] += xf * wv.w;
  }

  // ---- LSTM cell combine (4 channels per thread)
  float4 gi = *(const float4*)(gact + (0 * 64 + mloc) * 68 + cb);
  float4 gf = *(const float4*)(gact + (1 * 64 + mloc) * 68 + cb);
  float4 gg = *(const float4*)(gact + (2 * 64 + mloc) * 68 + cb);
  float4 go = *(const float4*)(gact + (3 * 64 + mloc) * 68 + cb);
  float cold[4] = {co4.x, co4.y, co4.z, co4.w};
  float iv[4] = {gi.x, gi.y, gi.z, gi.w};
  float fv[4] = {gf.x, gf.y, gf.z, gf.w};
  float gv[4] = {gg.x, gg.y, gg.z, gg.w};
  float ov[4] = {go.x, go.y, go.z, go.w};
  float cn4[4], h4[4];
  union { unsigned short hv[4]; uint2 q; } hu;
  #pragma unroll
  for (int e = 0; e < 4; e++) {
    float cn = fv[e] * cold[e] + iv[e] * gv[e];
    float h  = ov[e] * tanh_fast(cn);
    cn4[e] = cn; h4[e] = h;
    hu.hv[e] = f2bf(h);
  }
  if (t < T_ - 1)                                 // c_{t+1} -> next out slab
    *(float4*)(out + outbase + TSLAB) = make_float4(cn4[0], cn4[1], cn4[2], cn4[3]);
  *(float4*)(out + outbase) = make_float4(h4[0] + res[0], h4[1] + res[1],
                                          h4[2] + res[2], h4[3] + res[3]);
  *(uint2*)(hnew + hbase) = hu.q;
}

extern "C" void kernel_launch(void* const* d_in, const int* in_sizes, int n_in,
                              void* d_out, int out_size, void* d_ws, size_t ws_size,
                              hipStream_t stream) {
  const float* x    = (const float*)d_in[0];
  const float* Wx   = (const float*)d_in[1];
  const float* Wh   = (const float*)d_in[2];
  const float* bias = (const float*)d_in[3];
  const float* Wp   = (const float*)d_in[4];
  const float* bp   = (const float*)d_in[5];
  float* out = (float*)d_out;

  unsigned short* WT = (unsigned short*)d_ws;
  unsigned short* h0 = (unsigned short*)((char*)d_ws + OFF_H0);
  unsigned short* h1 = (unsigned short*)((char*)d_ws + OFF_H1);

  hipLaunchKernelGGL(prep_weights, dim3(1120), dim3(256), 0, stream, Wx, Wh, WT);
  hipLaunchKernelGGL(prep_zero_h, dim3(1024), dim3(256), 0, stream,
                     (float4*)((char*)d_ws + OFF_H0));
  hipLaunchKernelGGL(prep_zero_c, dim3(1024), dim3(256), 0, stream, out);

  for (int t = 0; t < T_; t++) {
    const unsigned short* hp = (t & 1) ? h1 : h0;
    unsigned short*       hn = (t & 1) ? h0 : h1;
    hipLaunchKernelGGL(step_kernel, dim3(256), dim3(1024), 0, stream,
                       x, bias, Wp, bp, WT, hp, hn, out, t);
  }
}

// Round 5
// 1144.864 us; speedup vs baseline: 1.0015x; 1.0015x over previous
//
#include <hip/hip_runtime.h>

// ResidualConvLSTM2D on MI355X (gfx950).
// Fused per-timestep implicit GEMM: z = conv3x3([x_t || h_{t-1}], [Wx || Wh]) via
// bf16 MFMA (16x16x32), fp32 LSTM cell, fp32 residual 1x1 conv.
//
// R8: R7 (reg-staged weight loads) regressed 45->77us with WRITE_SIZE 66->187MB
// while FETCH barely moved. Diagnosis: SPILLS, not memory behavior - VGPR_Count
// stayed 64 while R7 added 24 live VGPRs (rA+rB) across the MFMA phases; spill
// stores (~170MB computed) match the excess WRITE, spill reloads L2-hit (98KB
// scratch/block) so FETCH didn't rise. R7 never tested the L2-allocation
// theory. Single lever this round: __launch_bounds__(1024,4) -> VGPR cap 128
// (16 waves = exactly 4/EU), so the staging regs live in registers.
// Theory under test (explains R3/R5/R6 all pinning at ~3TB/s on ~141MB of
// weight requests, and R6's counted-vmcnt null = throughput wall): LDS-DMA
// (global_load_lds) does not allocate into L2, so every phase's weight walk
// transits the L2-miss path; normal vector loads allocate -> 31/32 blocks per
// XCD hit L2 and the wall collapses.
//
// ws layout (<4.79 MB of ~8 MB):
//   [0, 573440)          WT staged bf16 [28][256][40] (step 27 zeroed)
//   [589824, +2MB)       h ping  bf16 [4][64][64][64]
//   [2686976, +2MB)      h pong  bf16
// Cell state c (fp32) lives inside d_out: c_t at out[b][t][...] (read before
// that address is overwritten with the output), c_{t+1} into slab t+1.
#define B_ 4
#define T_ 16
#define H_ 64
#define W_ 64
#define CIN 32
#define F_ 64
#define NCH 256
#define KSTEPS 27
#define NPHASE 14
#define WSTEP 10240           // shorts per K-step weight image [256][40]
#define PHS   20480           // shorts per phase (2 K-steps)
#define TSLAB (H_ * W_ * F_)  // floats between (b,t) and (b,t+1)

#define OFF_H0 589824
#define OFF_H1 2686976

typedef __attribute__((ext_vector_type(8))) short short8;
typedef __attribute__((ext_vector_type(4))) float floatx4;

__device__ __forceinline__ unsigned short f2bf(float f) {
  union { float f; unsigned u; } v; v.f = f;
  unsigned r = v.u + 0x7FFFu + ((v.u >> 16) & 1u);   // round-to-nearest-even
  return (unsigned short)(r >> 16);
}

// tanh via hardware exp2: tanh(z) = 1 - 2/(exp(2z)+1). rcp approx (~1 ulp) is
// far inside the 4e-2 abs threshold. Saturates correctly for |z| large.
__device__ __forceinline__ float tanh_fast(float z) {
  float e = __expf(2.0f * z);
  return 1.0f - 2.0f * __builtin_amdgcn_rcpf(e + 1.0f);
}

// Staging image: WT[s][n][c], c in [0,40); c<32 -> weight for k = s*32+c of
// output channel n (k = tap*96 + ch; ch<32 from Wx else Wh); pad/step-27 -> 0.
__global__ void prep_weights(const float* __restrict__ Wx, const float* __restrict__ Wh,
                             unsigned short* __restrict__ WT) {
  int idx = blockIdx.x * 256 + threadIdx.x;            // 0..286719
  int s = idx / WSTEP;
  int r = idx - s * WSTEP;
  int n = r / 40;
  int c = r - n * 40;
  unsigned short v = 0;
  if (c < 32 && s < KSTEPS) {
    int k  = s * 32 + c;
    int g  = k / 96;
    int ch = k - g * 96;
    float f = (ch < CIN) ? Wx[(g * CIN + ch) * NCH + n]
                         : Wh[(g * F_ + (ch - CIN)) * NCH + n];
    v = f2bf(f);
  }
  WT[idx] = v;
}

// Zero h ping+pong (4 MB in ws).
__global__ void prep_zero_h(float4* __restrict__ p) {
  int idx = blockIdx.x * 256 + threadIdx.x;
  p[idx] = make_float4(0.f, 0.f, 0.f, 0.f);
}

// Zero c0 = out slabs [b][0][...].
__global__ void prep_zero_c(float* __restrict__ out) {
  int idx = blockIdx.x * 256 + threadIdx.x;            // float4 units
  int b = idx >> 16;
  int i = idx & 65535;
  ((float4*)(out + (size_t)b * (T_ * TSLAB)))[i] = make_float4(0.f, 0.f, 0.f, 0.f);
}

// Load one phase tile (40960 B = 2560 dwordx4) into regs: threads 0..1023 take
// slots {tid, tid+1024}, threads 0..511 additionally slot tid+2048.
// Normal vector loads -> L1/L2 allocate (this is the point of R8).
__device__ __forceinline__ void load_ph(const unsigned short* __restrict__ src,
                                        uint4 (&r)[3], int tid) {
  const uint4* s = (const uint4*)src;
  r[0] = s[tid];
  r[1] = s[tid + 1024];
  if (tid < 512) r[2] = s[tid + 2048];
}

// Mirror the same linear slot mapping into LDS (consecutive 16B per lane:
// 2-way bank aliasing = free).
__device__ __forceinline__ void write_ph(short* dst, uint4 (&r)[3], int tid) {
  uint4* d = (uint4*)dst;
  d[tid]        = r[0];
  d[tid + 1024] = r[1];
  if (tid < 512) d[tid + 2048] = r[2];
}

__global__ __launch_bounds__(1024, 4)
void step_kernel(const float* __restrict__ x, const float* __restrict__ bias,
                 const float* __restrict__ Wp, const float* __restrict__ bp,
                 const unsigned short* __restrict__ WT,
                 const unsigned short* __restrict__ hprev,
                 unsigned short* __restrict__ hnew,
                 float* __restrict__ out, int t)
{
  // LDS: patch [4][34][104] sh (28288) | wb0 [2][256][40] sh (40960) | wb1.
  // epilogue reuse: gact [256][68] fp32 (69632 B) at 0, WpL 8 KB at 69632.
  __shared__ __align__(16) char smem[110208];
  short* patch = (short*)smem;
  short* wb0   = (short*)(smem + 28288);
  short* wb1   = (short*)(smem + 69248);
  float* gact  = (float*)smem;
  float* WpL   = (float*)(smem + 69632);

  const int tid  = threadIdx.x;
  const int w    = tid >> 6;               // 0..15
  const int lane = tid & 63;
  const int quad = lane >> 4;
  const int lr   = lane & 15;
  const int gate = w >> 2;                 // wave's gate (i,f,c,o)
  const int mq   = w & 3;                  // wave's M-quarter (16 pixels)

  // bijective XCD swizzle: 256 blocks, 8 XCDs, 32 consecutive bids per XCD.
  const int raw = blockIdx.x;
  const int bid = (raw & 7) * 32 + (raw >> 3);
  const int b   = bid >> 6;
  const int rem = bid & 63;
  const int y0  = (rem >> 1) << 1;   // 2-row tile
  const int x0  = (rem & 1) << 5;    // 32-col half

  uint4 rA[3], rB[3];

  // ---- issue phase-0 weight loads (T0 -> rA) immediately
  load_ph(WT, rA, tid);
  __builtin_amdgcn_sched_barrier(0);

  // ---- stage input patch: 4 rows x 34 cols x 96 ch (x bf16 | h bf16),
  // split per entry into x-half / h-half across 272 threads.
  if (tid < 272) {
    int e = tid >> 1, half = tid & 1;
    int sy = e / 34, sx = e - sy * 34;
    int yy = y0 + sy - 1, xx = x0 + sx - 1;
    short* dst = patch + e * 104;
    bool in = (yy >= 0 && yy < H_ && xx >= 0 && xx < W_);
    if (half == 0) {                      // x channels 0..31 -> bf16
      if (in) {
        const float4* xs = (const float4*)(x + ((((b * T_ + t) * H_ + yy) * W_ + xx) * CIN));
        #pragma unroll
        for (int j = 0; j < 4; j++) {
          float4 f0 = xs[2 * j];
          float4 f1 = xs[2 * j + 1];
          union { short8 v; unsigned short u[8]; } pk;
          pk.u[0] = f2bf(f0.x); pk.u[1] = f2bf(f0.y); pk.u[2] = f2bf(f0.z); pk.u[3] = f2bf(f0.w);
          pk.u[4] = f2bf(f1.x); pk.u[5] = f2bf(f1.y); pk.u[6] = f2bf(f1.z); pk.u[7] = f2bf(f1.w);
          ((short8*)dst)[j] = pk.v;
        }
      } else {
        uint4 z = make_uint4(0, 0, 0, 0);
        uint4* d4 = (uint4*)dst;
        #pragma unroll
        for (int j = 0; j < 4; j++) d4[j] = z;
      }
    } else {                              // h channels (already bf16)
      uint4* d2 = (uint4*)(dst + 32);
      if (in) {
        const uint4* hs = (const uint4*)(hprev + ((b * H_ + yy) * W_ + xx) * F_);
        #pragma unroll
        for (int j = 0; j < 8; j++) d2[j] = hs[j];
      } else {
        uint4 z = make_uint4(0, 0, 0, 0);
        #pragma unroll
        for (int j = 0; j < 8; j++) d2[j] = z;
      }
    }
  }

  // ---- issue phase-1 weight loads (T1 -> rB)
  load_ph(WT + PHS, rB, tid);

  float bias_r[4];
  #pragma unroll
  for (int nf = 0; nf < 4; nf++) bias_r[nf] = bias[gate * 64 + nf * 16 + lr];

  floatx4 acc[4];
  #pragma unroll
  for (int nf = 0; nf < 4; nf++) acc[nf] = (floatx4){0.f, 0.f, 0.f, 0.f};

  // wave's A-row (pixel) for the MFMA A operand
  const int px = mq * 16 + lr;            // 0..63
  const int ty = px >> 5, tx = px & 31;

  // ---- prologue drain: patch + T0 + T1 + bias all retired, then commit T0.
  asm volatile("s_waitcnt vmcnt(0) lgkmcnt(0)" ::: "memory");
  __builtin_amdgcn_sched_barrier(0);
  write_ph(wb0, rA, tid);
  asm volatile("s_waitcnt lgkmcnt(0)" ::: "memory");
  __builtin_amdgcn_sched_barrier(0);
  __builtin_amdgcn_s_barrier();
  __builtin_amdgcn_sched_barrier(0);

  // ---- K loop: 14 phases of 2 K-steps (BK=64) over K=864.
  // Phase p: issue T(p+2) loads (parity p&1 -> rA/rB), compute from buf[p&1],
  // counted-vmcnt wait so T(p+1) regs are landed (one full phase of cover),
  // ds_write T(p+1) -> buf[(p+1)&1], lgkm drain, barrier. Never vmcnt(0)
  // mid-loop while newer loads fly.
  const unsigned short* wsrc = WT + 2 * PHS;
  for (int p = 0; p < NPHASE; p++) {
    short* cur = (p & 1) ? wb1 : wb0;
    short* nxt = (p & 1) ? wb0 : wb1;
    if (p < NPHASE - 2) {
      if ((p & 1) == 0) load_ph(wsrc, rA, tid);
      else              load_ph(wsrc, rB, tid);
      wsrc += PHS;
      __builtin_amdgcn_sched_barrier(0);   // pin issue point at phase start
    }
    int s0 = 2 * p;
    #pragma unroll
    for (int half = 0; half < 2; half++) {
      int s = s0 + half;
      if (s < KSTEPS) {
        int g  = s / 3;
        int c0 = (s - g * 3) * 32;
        int dy = g / 3, dx = g - dy * 3;
        short8 afr = *(const short8*)(patch + ((ty + dy) * 34 + tx + dx) * 104 + c0 + quad * 8);
        #pragma unroll
        for (int nf = 0; nf < 4; nf++) {
          short8 bfr = *(const short8*)(cur + half * WSTEP + (gate * 64 + nf * 16 + lr) * 40 + quad * 8);
          acc[nf] = __builtin_amdgcn_mfma_f32_16x16x32_bf16(afr, bfr, acc[nf], 0, 0, 0);
        }
      }
    }
    __builtin_amdgcn_sched_barrier(0);
    if (p < NPHASE - 1) {
      if (p < NPHASE - 2) {
        // newer T(p+2) loads stay in flight: 3 for tid<512 waves, else 2.
        if (tid < 512) asm volatile("s_waitcnt vmcnt(3)" ::: "memory");
        else           asm volatile("s_waitcnt vmcnt(2)" ::: "memory");
      } else {
        asm volatile("s_waitcnt vmcnt(0)" ::: "memory");   // tail: nothing newer
      }
      __builtin_amdgcn_sched_barrier(0);
      if ((p & 1) == 0) write_ph(nxt, rB, tid);   // T(p+1) parity = !(p&1)
      else              write_ph(nxt, rA, tid);
    }
    asm volatile("s_waitcnt lgkmcnt(0)" ::: "memory");
    __builtin_amdgcn_sched_barrier(0);
    __builtin_amdgcn_s_barrier();
    __builtin_amdgcn_sched_barrier(0);
  }

  // ---- epilogue phase 1: activations -> gact[(gate*64+px)*68 + ch], WpL
  #pragma unroll
  for (int nf = 0; nf < 4; nf++)
    #pragma unroll
    for (int r = 0; r < 4; r++) {
      int mm = quad * 4 + r;                      // D row = quad*4 + reg
      float z = acc[nf][r] + bias_r[nf];
      float a;
      if (gate == 2) a = tanh_fast(z);            // candidate gate
      else {                                      // hard_sigmoid for i, f, o
        a = __builtin_fmaf(z, 0.2f, 0.5f);
        a = fminf(fmaxf(a, 0.f), 1.f);
      }
      gact[(gate * 64 + mq * 16 + mm) * 68 + nf * 16 + lr] = a;
    }
  if (tid < 512)                                  // Wp -> LDS (512 float4)
    ((float4*)WpL)[tid] = ((const float4*)Wp)[tid];

  const int mloc = tid >> 4;                      // pixel in tile (0..63)
  const int cb   = (tid & 15) * 4;                // 4-channel slice
  const int tyo  = mloc >> 5, txo = mloc & 31;
  const int gy   = y0 + tyo, gx = x0 + txo;
  const int hbase   = ((b * H_ + gy) * W_ + gx) * F_ + cb;
  const int outbase = (((b * T_ + t) * H_ + gy) * W_ + gx) * F_ + cb;

  // prefetch x (residual) and c_t (global) before the barrier
  float xv[32];
  {
    const float4* xs = (const float4*)(x + ((((b * T_ + t) * H_ + gy) * W_ + gx) * CIN));
    #pragma unroll
    for (int j = 0; j < 8; j++) {
      float4 f = xs[j];
      xv[4 * j] = f.x; xv[4 * j + 1] = f.y; xv[4 * j + 2] = f.z; xv[4 * j + 3] = f.w;
    }
  }
  float4 co4 = *(const float4*)(out + outbase);

  __syncthreads();                                // gact + WpL visible

  // ---- residual 1x1 conv (fp32), 4 output channels per thread
  float res[4];
  #pragma unroll
  for (int j = 0; j < 4; j++) res[j] = bp[cb + j];
  #pragma unroll
  for (int ci = 0; ci < 32; ci++) {
    float xf = xv[ci];
    float4 wv = *(const float4*)(WpL + ci * 64 + cb);
    res[0] += xf * wv.x; res[1] += xf * wv.y; res[2] += xf * wv.z; res[3] += xf * wv.w;
  }

  // ---- LSTM cell combine (4 channels per thread)
  float4 gi = *(const float4*)(gact + (0 * 64 + mloc) * 68 + cb);
  float4 gf = *(const float4*)(gact + (1 * 64 + mloc) * 68 + cb);
  float4 gg = *(const float4*)(gact + (2 * 64 + mloc) * 68 + cb);
  float4 go = *(const float4*)(gact + (3 * 64 + mloc) * 68 + cb);
  float cold[4] = {co4.x, co4.y, co4.z, co4.w};
  float iv[4] = {gi.x, gi.y, gi.z, gi.w};
  float fv[4] = {gf.x, gf.y, gf.z, gf.w};
  float gv[4] = {gg.x, gg.y, gg.z, gg.w};
  float ov[4] = {go.x, go.y, go.z, go.w};
  float cn4[4], h4[4];
  union { unsigned short hv[4]; uint2 q; } hu;
  #pragma unroll
  for (int e = 0; e < 4; e++) {
    float cn = fv[e] * cold[e] + iv[e] * gv[e];
    float h  = ov[e] * tanh_fast(cn);
    cn4[e] = cn; h4[e] = h;
    hu.hv[e] = f2bf(h);
  }
  if (t < T_ - 1)                                 // c_{t+1} -> next out slab
    *(float4*)(out + outbase + TSLAB) = make_float4(cn4[0], cn4[1], cn4[2], cn4[3]);
  *(float4*)(out + outbase) = make_float4(h4[0] + res[0], h4[1] + res[1],
                                          h4[2] + res[2], h4[3] + res[3]);
  *(uint2*)(hnew + hbase) = hu.q;
}

extern "C" void kernel_launch(void* const* d_in, const int* in_sizes, int n_in,
                              void* d_out, int out_size, void* d_ws, size_t ws_size,
                              hipStream_t stream) {
  const float* x    = (const float*)d_in[0];
  const float* Wx   = (const float*)d_in[1];
  const float* Wh   = (const float*)d_in[2];
  const float* bias = (const float*)d_in[3];
  const float* Wp   = (const float*)d_in[4];
  const float* bp   = (const float*)d_in[5];
  float* out = (float*)d_out;

  unsigned short* WT = (unsigned short*)d_ws;
  unsigned short* h0 = (unsigned short*)((char*)d_ws + OFF_H0);
  unsigned short* h1 = (unsigned short*)((char*)d_ws + OFF_H1);

  hipLaunchKernelGGL(prep_weights, dim3(1120), dim3(256), 0, stream, Wx, Wh, WT);
  hipLaunchKernelGGL(prep_zero_h, dim3(1024), dim3(256), 0, stream,
                     (float4*)((char*)d_ws + OFF_H0));
  hipLaunchKernelGGL(prep_zero_c, dim3(1024), dim3(256), 0, stream, out);

  for (int t = 0; t < T_; t++) {
    const unsigned short* hp = (t & 1) ? h1 : h0;
    unsigned short*       hn = (t & 1) ? h0 : h1;
    hipLaunchKernelGGL(step_kernel, dim3(256), dim3(1024), 0, stream,
                       x, bias, Wp, bp, WT, hp, hn, out, t);
  }
}

// Round 6
// 682.359 us; speedup vs baseline: 1.6803x; 1.6778x over previous
//
#include <hip/hip_runtime.h>

// ResidualConvLSTM2D on MI355X (gfx950).
// Fused per-timestep implicit GEMM: z = conv3x3([x_t || h_{t-1}], [Wx || Wh]) via
// bf16 MFMA (16x16x32), fp32 LSTM cell, fp32 residual 1x1 conv.
//
// R9: broadcast-contention theory. R3/R5/R6 all pin at ~4Kcy per K-step despite
// 4x occupancy (R5) and 2-deep counted-vmcnt prefetch (R6, exact null). L2 BW
// (143MB@34.5TB/s=4us), HBM (FETCH ~25MB of weights), and per-CU DMA rate
// (m97: 53B/cy/CU) all ruled out. Unique property here: all 256 blocks stream
// the SAME 0.57MB weight image in lockstep -> within an XCD, 32 CUs request the
// identical cache line in the same cycle window; the L2 bank serializes the 32
// responses -> effective ~5.7B/cy/CU (observed). Fix: per-block PHASE ROTATION
// (rot = bid % 14, phases walked mod 14; K-sum is order-independent). Blocks on
// one XCD spread across ~14 phase offsets -> same-line collision drops 32x.
// Base = R5 verbatim (44us/dispatch) + rotation; single lever.
//
// ws layout (<4.79 MB of ~8 MB):
//   [0, 573440)          WT staged bf16 [28][256][40] (step 27 zeroed)
//   [589824, +2MB)       h ping  bf16 [4][64][64][64]
//   [2686976, +2MB)      h pong  bf16
// Cell state c (fp32) lives inside d_out: c_t at out[b][t][...] (read before
// that address is overwritten with the output), c_{t+1} into slab t+1.
#define B_ 4
#define T_ 16
#define H_ 64
#define W_ 64
#define CIN 32
#define F_ 64
#define NCH 256
#define KSTEPS 27
#define NPHASE 14
#define WSTEP 10240           // shorts per K-step weight image [256][40]
#define PHS   20480           // shorts per phase (2 K-steps)
#define TSLAB (H_ * W_ * F_)  // floats between (b,t) and (b,t+1)

#define OFF_H0 589824
#define OFF_H1 2686976

typedef __attribute__((ext_vector_type(8))) short short8;
typedef __attribute__((ext_vector_type(4))) float floatx4;
typedef __attribute__((address_space(3))) unsigned int  lds_u32;
typedef __attribute__((address_space(1))) const unsigned int g_u32;

__device__ __forceinline__ unsigned short f2bf(float f) {
  union { float f; unsigned u; } v; v.f = f;
  unsigned r = v.u + 0x7FFFu + ((v.u >> 16) & 1u);   // round-to-nearest-even
  return (unsigned short)(r >> 16);
}

// tanh via hardware exp2: tanh(z) = 1 - 2/(exp(2z)+1). rcp approx (~1 ulp) is
// far inside the 4e-2 abs threshold. Saturates correctly for |z| large.
__device__ __forceinline__ float tanh_fast(float z) {
  float e = __expf(2.0f * z);
  return 1.0f - 2.0f * __builtin_amdgcn_rcpf(e + 1.0f);
}

// Staging image: WT[s][n][c], c in [0,40); c<32 -> weight for k = s*32+c of
// output channel n (k = tap*96 + ch; ch<32 from Wx else Wh); pad/step-27 -> 0.
__global__ void prep_weights(const float* __restrict__ Wx, const float* __restrict__ Wh,
                             unsigned short* __restrict__ WT) {
  int idx = blockIdx.x * 256 + threadIdx.x;            // 0..286719
  int s = idx / WSTEP;
  int r = idx - s * WSTEP;
  int n = r / 40;
  int c = r - n * 40;
  unsigned short v = 0;
  if (c < 32 && s < KSTEPS) {
    int k  = s * 32 + c;
    int g  = k / 96;
    int ch = k - g * 96;
    float f = (ch < CIN) ? Wx[(g * CIN + ch) * NCH + n]
                         : Wh[(g * F_ + (ch - CIN)) * NCH + n];
    v = f2bf(f);
  }
  WT[idx] = v;
}

// Zero h ping+pong (4 MB in ws).
__global__ void prep_zero_h(float4* __restrict__ p) {
  int idx = blockIdx.x * 256 + threadIdx.x;
  p[idx] = make_float4(0.f, 0.f, 0.f, 0.f);
}

// Zero c0 = out slabs [b][0][...].
__global__ void prep_zero_c(float* __restrict__ out) {
  int idx = blockIdx.x * 256 + threadIdx.x;            // float4 units
  int b = idx >> 16;
  int i = idx & 65535;
  ((float4*)(out + (size_t)b * (T_ * TSLAB)))[i] = make_float4(0.f, 0.f, 0.f, 0.f);
}

// Stage one phase's weight tile (2 K-steps, 40960 B) as 40 x 1KB chunks
// round-robined across 16 waves. LDS dst is wave-uniform + lane*16.
__device__ __forceinline__ void stage_wt2(const unsigned short* __restrict__ src,
                                          short* dstbuf, int w, int lane) {
  __attribute__((address_space(3))) unsigned short* d =
      (__attribute__((address_space(3))) unsigned short*)dstbuf;
  const unsigned short* s = src + lane * 8;
  __builtin_amdgcn_global_load_lds((g_u32*)(s + w * 512),
                                   (lds_u32*)(d + w * 512), 16, 0, 0);
  __builtin_amdgcn_global_load_lds((g_u32*)(s + (w + 16) * 512),
                                   (lds_u32*)(d + (w + 16) * 512), 16, 0, 0);
  if (w < 8)                               // chunks 32..39 (wave-uniform branch)
    __builtin_amdgcn_global_load_lds((g_u32*)(s + (w + 32) * 512),
                                     (lds_u32*)(d + (w + 32) * 512), 16, 0, 0);
}

__global__ __launch_bounds__(1024, 1)
void step_kernel(const float* __restrict__ x, const float* __restrict__ bias,
                 const float* __restrict__ Wp, const float* __restrict__ bp,
                 const unsigned short* __restrict__ WT,
                 const unsigned short* __restrict__ hprev,
                 unsigned short* __restrict__ hnew,
                 float* __restrict__ out, int t)
{
  // LDS: patch [4][34][104] sh (28288) | bl0 [2][256][40] sh (40960) | bl1.
  // epilogue reuse: gact [256][68] fp32 (69632 B) at 0, WpL 8 KB at 69632.
  __shared__ __align__(16) char smem[110208];
  short* patch = (short*)smem;
  short* bl0   = (short*)(smem + 28288);
  short* bl1   = (short*)(smem + 69248);
  float* gact  = (float*)smem;
  float* WpL   = (float*)(smem + 69632);

  const int tid  = threadIdx.x;
  const int w    = tid >> 6;               // 0..15
  const int lane = tid & 63;
  const int quad = lane >> 4;
  const int lr   = lane & 15;
  const int gate = w >> 2;                 // wave's gate (i,f,c,o)
  const int mq   = w & 3;                  // wave's M-quarter (16 pixels)

  // bijective XCD swizzle: 256 blocks, 8 XCDs, 32 consecutive bids per XCD.
  const int raw = blockIdx.x;
  const int bid = (raw & 7) * 32 + (raw >> 3);
  const int b   = bid >> 6;
  const int rem = bid & 63;
  const int y0  = (rem >> 1) << 1;   // 2-row tile
  const int x0  = (rem & 1) << 5;    // 32-col half

  // phase rotation: blocks on one XCD have consecutive bids -> rot spreads
  // 0..13 within the XCD, desynchronizing the weight-line requests.
  const int rot = bid % NPHASE;

  // ---- prefetch rotated phase-0 weights into bl0 (in flight during patch staging)
  stage_wt2(WT + rot * PHS, bl0, w, lane);

  // ---- stage input patch: 4 rows x 34 cols x 96 ch (x bf16 | h bf16),
  // split per entry into x-half / h-half across 272 threads.
  if (tid < 272) {
    int e = tid >> 1, half = tid & 1;
    int sy = e / 34, sx = e - sy * 34;
    int yy = y0 + sy - 1, xx = x0 + sx - 1;
    short* dst = patch + e * 104;
    bool in = (yy >= 0 && yy < H_ && xx >= 0 && xx < W_);
    if (half == 0) {                      // x channels 0..31 -> bf16
      if (in) {
        const float4* xs = (const float4*)(x + ((((b * T_ + t) * H_ + yy) * W_ + xx) * CIN));
        #pragma unroll
        for (int j = 0; j < 4; j++) {
          float4 f0 = xs[2 * j];
          float4 f1 = xs[2 * j + 1];
          union { short8 v; unsigned short u[8]; } pk;
          pk.u[0] = f2bf(f0.x); pk.u[1] = f2bf(f0.y); pk.u[2] = f2bf(f0.z); pk.u[3] = f2bf(f0.w);
          pk.u[4] = f2bf(f1.x); pk.u[5] = f2bf(f1.y); pk.u[6] = f2bf(f1.z); pk.u[7] = f2bf(f1.w);
          ((short8*)dst)[j] = pk.v;
        }
      } else {
        uint4 z = make_uint4(0, 0, 0, 0);
        uint4* d4 = (uint4*)dst;
        #pragma unroll
        for (int j = 0; j < 4; j++) d4[j] = z;
      }
    } else {                              // h channels (already bf16)
      uint4* d2 = (uint4*)(dst + 32);
      if (in) {
        const uint4* hs = (const uint4*)(hprev + ((b * H_ + yy) * W_ + xx) * F_);
        #pragma unroll
        for (int j = 0; j < 8; j++) d2[j] = hs[j];
      } else {
        uint4 z = make_uint4(0, 0, 0, 0);
        #pragma unroll
        for (int j = 0; j < 8; j++) d2[j] = z;
      }
    }
  }

  float bias_r[4];
  #pragma unroll
  for (int nf = 0; nf < 4; nf++) bias_r[nf] = bias[gate * 64 + nf * 16 + lr];

  floatx4 acc[4];
  #pragma unroll
  for (int nf = 0; nf < 4; nf++) acc[nf] = (floatx4){0.f, 0.f, 0.f, 0.f};

  // wave's A-row (pixel) for the MFMA A operand
  const int px = mq * 16 + lr;            // 0..63
  const int ty = px >> 5, tx = px & 31;

  __syncthreads();   // patch staged + bl0 DMA drained (vmcnt(0) before barrier)

  // ---- K loop: 14 phases of 2 K-steps (BK=64) over K=864, each block walking
  // phases (p + rot) mod 14; double-buffered weight tile, ONE barrier per
  // phase; prefetch next rotated phase during compute of current.
  for (int p = 0; p < NPHASE; p++) {
    short* cur = (p & 1) ? bl1 : bl0;
    if (p < NPHASE - 1) {
      int qn = p + 1 + rot; if (qn >= NPHASE) qn -= NPHASE;
      stage_wt2(WT + qn * PHS, (p & 1) ? bl0 : bl1, w, lane);
    }
    int q = p + rot; if (q >= NPHASE) q -= NPHASE;
    #pragma unroll
    for (int half = 0; half < 2; half++) {
      int s = 2 * q + half;
      if (s < KSTEPS) {
        int g  = s / 3;
        int c0 = (s - g * 3) * 32;
        int dy = g / 3, dx = g - dy * 3;
        short8 afr = *(const short8*)(patch + ((ty + dy) * 34 + tx + dx) * 104 + c0 + quad * 8);
        #pragma unroll
        for (int nf = 0; nf < 4; nf++) {
          short8 bfr = *(const short8*)(cur + half * WSTEP + (gate * 64 + nf * 16 + lr) * 40 + quad * 8);
          acc[nf] = __builtin_amdgcn_mfma_f32_16x16x32_bf16(afr, bfr, acc[nf], 0, 0, 0);
        }
      }
    }
    __syncthreads();   // everyone done with cur; prefetch DMA drained
  }

  // ---- epilogue phase 1: activations -> gact[(gate*64+px)*68 + ch], WpL
  #pragma unroll
  for (int nf = 0; nf < 4; nf++)
    #pragma unroll
    for (int r = 0; r < 4; r++) {
      int mm = quad * 4 + r;                      // D row = quad*4 + reg
      float z = acc[nf][r] + bias_r[nf];
      float a;
      if (gate == 2) a = tanh_fast(z);            // candidate gate
      else {                                      // hard_sigmoid for i, f, o
        a = __builtin_fmaf(z, 0.2f, 0.5f);
        a = fminf(fmaxf(a, 0.f), 1.f);
      }
      gact[(gate * 64 + mq * 16 + mm) * 68 + nf * 16 + lr] = a;
    }
  if (tid < 512)                                  // Wp -> LDS (512 float4)
    ((float4*)WpL)[tid] = ((const float4*)Wp)[tid];

  const int mloc = tid >> 4;                      // pixel in tile (0..63)
  const int cb   = (tid & 15) * 4;                // 4-channel slice
  const int tyo  = mloc >> 5, txo = mloc & 31;
  const int gy   = y0 + tyo, gx = x0 + txo;
  const int hbase   = ((b * H_ + gy) * W_ + gx) * F_ + cb;
  const int outbase = (((b * T_ + t) * H_ + gy) * W_ + gx) * F_ + cb;

  // prefetch x (residual) and c_t (global) before the barrier
  float xv[32];
  {
    const float4* xs = (const float4*)(x + ((((b * T_ + t) * H_ + gy) * W_ + gx) * CIN));
    #pragma unroll
    for (int j = 0; j < 8; j++) {
      float4 f = xs[j];
      xv[4 * j] = f.x; xv[4 * j + 1] = f.y; xv[4 * j + 2] = f.z; xv[4 * j + 3] = f.w;
    }
  }
  float4 co4 = *(const float4*)(out + outbase);

  __syncthreads();                                // gact + WpL visible

  // ---- residual 1x1 conv (fp32), 4 output channels per thread
  float res[4];
  #pragma unroll
  for (int j = 0; j < 4; j++) res[j] = bp[cb + j];
  #pragma unroll
  for (int ci = 0; ci < 32; ci++) {
    float xf = xv[ci];
    float4 wv = *(const float4*)(WpL + ci * 64 + cb);
    res[0] += xf * wv.x; res[1] += xf * wv.y; res[2] += xf * wv.z; res[3] += xf * wv.w;
  }

  // ---- LSTM cell combine (4 channels per thread)
  float4 gi = *(const float4*)(gact + (0 * 64 + mloc) * 68 + cb);
  float4 gf = *(const float4*)(gact + (1 * 64 + mloc) * 68 + cb);
  float4 gg = *(const float4*)(gact + (2 * 64 + mloc) * 68 + cb);
  float4 go = *(const float4*)(gact + (3 * 64 + mloc) * 68 + cb);
  float cold[4] = {co4.x, co4.y, co4.z, co4.w};
  float iv[4] = {gi.x, gi.y, gi.z, gi.w};
  float fv[4] = {gf.x, gf.y, gf.z, gf.w};
  float gv[4] = {gg.x, gg.y, gg.z, gg.w};
  float ov[4] = {go.x, go.y, go.z, go.w};
  float cn4[4], h4[4];
  union { unsigned short hv[4]; uint2 q; } hu;
  #pragma unroll
  for (int e = 0; e < 4; e++) {
    float cn = fv[e] * cold[e] + iv[e] * gv[e];
    float h  = ov[e] * tanh_fast(cn);
    cn4[e] = cn; h4[e] = h;
    hu.hv[e] = f2bf(h);
  }
  if (t < T_ - 1)                                 // c_{t+1} -> next out slab
    *(float4*)(out + outbase + TSLAB) = make_float4(cn4[0], cn4[1], cn4[2], cn4[3]);
  *(float4*)(out + outbase) = make_float4(h4[0] + res[0], h4[1] + res[1],
                                          h4[2] + res[2], h4[3] + res[3]);
  *(uint2*)(hnew + hbase) = hu.q;
}

extern "C" void kernel_launch(void* const* d_in, const int* in_sizes, int n_in,
                              void* d_out, int out_size, void* d_ws, size_t ws_size,
                              hipStream_t stream) {
  const float* x    = (const float*)d_in[0];
  const float* Wx   = (const float*)d_in[1];
  const float* Wh   = (const float*)d_in[2];
  const float* bias = (const float*)d_in[3];
  const float* Wp   = (const float*)d_in[4];
  const float* bp   = (const float*)d_in[5];
  float* out = (float*)d_out;

  unsigned short* WT = (unsigned short*)d_ws;
  unsigned short* h0 = (unsigned short*)((char*)d_ws + OFF_H0);
  unsigned short* h1 = (unsigned short*)((char*)d_ws + OFF_H1);

  hipLaunchKernelGGL(prep_weights, dim3(1120), dim3(256), 0, stream, Wx, Wh, WT);
  hipLaunchKernelGGL(prep_zero_h, dim3(1024), dim3(256), 0, stream,
                     (float4*)((char*)d_ws + OFF_H0));
  hipLaunchKernelGGL(prep_zero_c, dim3(1024), dim3(256), 0, stream, out);

  for (int t = 0; t < T_; t++) {
    const unsigned short* hp = (t & 1) ? h1 : h0;
    unsigned short*       hn = (t & 1) ? h0 : h1;
    hipLaunchKernelGGL(step_kernel, dim3(256), dim3(1024), 0, stream,
                       x, bias, Wp, bp, WT, hp, hn, out, t);
  }
}